// Round 1
// baseline (7879.536 us; speedup 1.0000x reference)
//
#include <hip/hip_runtime.h>

#define NNODES 50000

// ---------------- scatter-add: agg[dst] += x[src], d features per edge -------
// One thread per (edge, 4-feature chunk). DQ = d/4, SHIFT = log2(DQ).
template<int DQ, int SHIFT>
__global__ __launch_bounds__(256) void scatter_add_kernel(
    const float* __restrict__ x, const int* __restrict__ src,
    const int* __restrict__ dst, float* __restrict__ agg, int E)
{
    int tid = blockIdx.x * 256 + threadIdx.x;
    int e = tid >> SHIFT;
    if (e >= E) return;
    int c = (tid & (DQ - 1)) << 2;
    int s = src[e];
    int d = dst[e];
    const float4 v = *(const float4*)(x + ((size_t)s << (SHIFT + 2)) + c);
    float* o = agg + ((size_t)d << (SHIFT + 2)) + c;
    atomicAdd(o + 0, v.x);
    atomicAdd(o + 1, v.y);
    atomicAdd(o + 2, v.z);
    atomicAdd(o + 3, v.w);
}

// ---------------- fused GEMM: out = leakyrelu([agg|h] @ [Wr|Ws]^T + b) -------
// A' = [agg | h]  (N x 2*d_in), B' = [Wr | Ws] (d_out x 2*d_in, row-major
// along k), out (N x d_out). 64x64 output tile, BK=16, 256 threads, 4x4 acc.
__global__ __launch_bounds__(256) void gemm_fused_kernel(
    const float* __restrict__ A0, const float* __restrict__ A1,
    const float* __restrict__ B0, const float* __restrict__ B1,
    const float* __restrict__ bias, float* __restrict__ out,
    int N, int d_in, int d_out)
{
    __shared__ float As[16][64];
    __shared__ float Bs[16][64];
    const int tid  = threadIdx.x;
    const int row0 = blockIdx.x * 64;
    const int col0 = blockIdx.y * 64;
    const int tx = tid & 15;    // col group
    const int ty = tid >> 4;    // row group
    const int lr = tid >> 2;        // 0..63 : row within tile for loads
    const int lk = (tid & 3) << 2;  // 0,4,8,12 : k offset within BK for loads

    float acc[4][4] = {};
    const int Ktot = 2 * d_in;

    for (int k0 = 0; k0 < Ktot; k0 += 16) {
        const int gk = k0 + lk;
        const float* Ap; const float* Bp; int kk;
        if (gk < d_in) { Ap = A0; Bp = B0; kk = gk; }
        else           { Ap = A1; Bp = B1; kk = gk - d_in; }

        const int n = row0 + lr;
        float4 av = make_float4(0.f, 0.f, 0.f, 0.f);
        if (n < NNODES) av = *(const float4*)(Ap + (size_t)n * d_in + kk);
        const float4 bv = *(const float4*)(Bp + (size_t)(col0 + lr) * d_in + kk);

        __syncthreads();   // protect As/Bs of previous iteration
        As[lk + 0][lr] = av.x; As[lk + 1][lr] = av.y;
        As[lk + 2][lr] = av.z; As[lk + 3][lr] = av.w;
        Bs[lk + 0][lr] = bv.x; Bs[lk + 1][lr] = bv.y;
        Bs[lk + 2][lr] = bv.z; Bs[lk + 3][lr] = bv.w;
        __syncthreads();

        #pragma unroll
        for (int k = 0; k < 16; k++) {
            const float4 a = *(const float4*)(&As[k][ty << 2]);
            const float4 b = *(const float4*)(&Bs[k][tx << 2]);
            acc[0][0] += a.x * b.x; acc[0][1] += a.x * b.y;
            acc[0][2] += a.x * b.z; acc[0][3] += a.x * b.w;
            acc[1][0] += a.y * b.x; acc[1][1] += a.y * b.y;
            acc[1][2] += a.y * b.z; acc[1][3] += a.y * b.w;
            acc[2][0] += a.z * b.x; acc[2][1] += a.z * b.y;
            acc[2][2] += a.z * b.z; acc[2][3] += a.z * b.w;
            acc[3][0] += a.w * b.x; acc[3][1] += a.w * b.y;
            acc[3][2] += a.w * b.z; acc[3][3] += a.w * b.w;
        }
    }

    const float4 bb = *(const float4*)(bias + col0 + (tx << 2));
    #pragma unroll
    for (int i = 0; i < 4; i++) {
        const int n = row0 + (ty << 2) + i;
        if (n < NNODES) {
            float4 r;
            r.x = acc[i][0] + bb.x;
            r.y = acc[i][1] + bb.y;
            r.z = acc[i][2] + bb.z;
            r.w = acc[i][3] + bb.w;
            r.x = r.x > 0.f ? r.x : 0.01f * r.x;
            r.y = r.y > 0.f ? r.y : 0.01f * r.y;
            r.z = r.z > 0.f ? r.z : 0.01f * r.z;
            r.w = r.w > 0.f ? r.w : 0.01f * r.w;
            *(float4*)(out + (size_t)n * d_out + col0 + (tx << 2)) = r;
        }
    }
}

extern "C" void kernel_launch(void* const* d_in, const int* in_sizes, int n_in,
                              void* d_out, int out_size, void* d_ws, size_t ws_size,
                              hipStream_t stream) {
    const int N = NNODES;
    const float* x  = (const float*)d_in[0];
    const int*   ei = (const int*)d_in[1];
    const int    E  = in_sizes[1] / 2;
    const int* src = ei;
    const int* dst = ei + E;

    const float* Wr[4] = { (const float*)d_in[2], (const float*)d_in[5],
                           (const float*)d_in[8], (const float*)d_in[11] };
    const float* Ws[4] = { (const float*)d_in[3], (const float*)d_in[6],
                           (const float*)d_in[9], (const float*)d_in[12] };
    const float* bb[4] = { (const float*)d_in[4], (const float*)d_in[7],
                           (const float*)d_in[10], (const float*)d_in[13] };

    float* out  = (float*)d_out;                     // h_final: N x 128
    float* emb  = out + (size_t)N * 128;             // emb:     N x 64
    float* agg  = (float*)d_ws;                      // N x 256 scratch
    float* hbuf = agg + (size_t)N * 256;             // N x 256 ping-pong

    const int rowBlocks = (N + 63) / 64;   // 782

    // ---- Layer 0: d_in=128 -> d_out=256, input x, output hbuf ----
    hipMemsetAsync(agg, 0, (size_t)N * 128 * sizeof(float), stream);
    {
        int total = E * 32;  // DQ=32
        scatter_add_kernel<32, 5><<<(total + 255) / 256, 256, 0, stream>>>(x, src, dst, agg, E);
        gemm_fused_kernel<<<dim3(rowBlocks, 4), 256, 0, stream>>>(
            agg, x, Wr[0], Ws[0], bb[0], hbuf, N, 128, 256);
    }

    // ---- Layer 1: 256 -> 64, input hbuf, output emb (in d_out) ----
    hipMemsetAsync(agg, 0, (size_t)N * 256 * sizeof(float), stream);
    {
        int total = E * 64;  // DQ=64
        scatter_add_kernel<64, 6><<<(total + 255) / 256, 256, 0, stream>>>(hbuf, src, dst, agg, E);
        gemm_fused_kernel<<<dim3(rowBlocks, 1), 256, 0, stream>>>(
            agg, hbuf, Wr[1], Ws[1], bb[1], emb, N, 256, 64);
    }

    // ---- Layer 2: 64 -> 256, input emb, output hbuf ----
    hipMemsetAsync(agg, 0, (size_t)N * 64 * sizeof(float), stream);
    {
        int total = E * 16;  // DQ=16
        scatter_add_kernel<16, 4><<<(total + 255) / 256, 256, 0, stream>>>(emb, src, dst, agg, E);
        gemm_fused_kernel<<<dim3(rowBlocks, 4), 256, 0, stream>>>(
            agg, emb, Wr[2], Ws[2], bb[2], hbuf, N, 64, 256);
    }

    // ---- Layer 3: 256 -> 128, input hbuf, output out ----
    hipMemsetAsync(agg, 0, (size_t)N * 256 * sizeof(float), stream);
    {
        int total = E * 64;  // DQ=64
        scatter_add_kernel<64, 6><<<(total + 255) / 256, 256, 0, stream>>>(hbuf, src, dst, agg, E);
        gemm_fused_kernel<<<dim3(rowBlocks, 2), 256, 0, stream>>>(
            agg, hbuf, Wr[3], Ws[3], bb[3], out, N, 256, 128);
    }
}

// Round 2
// 906.219 us; speedup vs baseline: 8.6950x; 8.6950x over previous
//
#include <hip/hip_runtime.h>

#define NNODES 50000

// ======================= CSR build (by destination) =========================
__global__ __launch_bounds__(256) void count_deg(const int* __restrict__ dst,
                                                 int* __restrict__ cnt, int E) {
    int e = blockIdx.x * 256 + threadIdx.x;
    if (e < E) atomicAdd(&cnt[dst[e]], 1);
}

// per-block exclusive scan; block totals to bsum
__global__ __launch_bounds__(256) void scan_block(const int* __restrict__ cnt,
                                                  int* __restrict__ rowptr,
                                                  int* __restrict__ bsum, int N) {
    __shared__ int s[256];
    int tid = threadIdx.x;
    int g = blockIdx.x * 256 + tid;
    int v = (g < N) ? cnt[g] : 0;
    s[tid] = v;
    __syncthreads();
    for (int off = 1; off < 256; off <<= 1) {
        int t = (tid >= off) ? s[tid - off] : 0;
        __syncthreads();
        s[tid] += t;
        __syncthreads();
    }
    if (g < N) rowptr[g] = s[tid] - v;       // exclusive
    if (tid == 255) bsum[blockIdx.x] = s[255];
}

// exclusive scan of block sums (nb <= 256), single block
__global__ __launch_bounds__(256) void scan_sums(int* __restrict__ bsum, int nb) {
    __shared__ int s[256];
    int tid = threadIdx.x;
    int v = (tid < nb) ? bsum[tid] : 0;
    s[tid] = v;
    __syncthreads();
    for (int off = 1; off < 256; off <<= 1) {
        int t = (tid >= off) ? s[tid - off] : 0;
        __syncthreads();
        s[tid] += t;
        __syncthreads();
    }
    if (tid < nb) bsum[tid] = s[tid] - v;    // exclusive
}

__global__ __launch_bounds__(256) void scan_add(int* __restrict__ rowptr,
                                                const int* __restrict__ bsum,
                                                int N, int E) {
    int g = blockIdx.x * 256 + threadIdx.x;
    if (g < N) rowptr[g] += bsum[blockIdx.x];
    if (g == 0) rowptr[N] = E;
}

__global__ __launch_bounds__(256) void fill_col(const int* __restrict__ src,
                                                const int* __restrict__ dst,
                                                const int* __restrict__ rowptr,
                                                int* __restrict__ cnt,
                                                int* __restrict__ col, int E) {
    int e = blockIdx.x * 256 + threadIdx.x;
    if (e < E) {
        int d = dst[e];
        int p = atomicAdd(&cnt[d], 1);
        col[rowptr[d] + p] = src[e];
    }
}

// ======================= gather-sum (no atomics) ============================
__device__ inline void vzero(float& a) { a = 0.f; }
__device__ inline void vzero(float2& a) { a.x = a.y = 0.f; }
__device__ inline void vzero(float4& a) { a.x = a.y = a.z = a.w = 0.f; }
__device__ inline void vadd(float& a, const float b) { a += b; }
__device__ inline void vadd(float2& a, const float2 b) { a.x += b.x; a.y += b.y; }
__device__ inline void vadd(float4& a, const float4 b) {
    a.x += b.x; a.y += b.y; a.z += b.z; a.w += b.w;
}

// one wave per node; lane covers sizeof(VT)/4 contiguous features; D = 64*VEC
template<typename VT, int D>
__global__ __launch_bounds__(256) void gather_sum(
    const float* __restrict__ x, const int* __restrict__ rowptr,
    const int* __restrict__ col, float* __restrict__ agg, int N)
{
    constexpr int LANEF = sizeof(VT) / 4;
    const int wave = threadIdx.x >> 6;
    const int lane = threadIdx.x & 63;
    const int node = blockIdx.x * 4 + wave;
    if (node >= N) return;
    const int beg = rowptr[node], end = rowptr[node + 1];
    VT acc; vzero(acc);
    const size_t off = (size_t)lane * LANEF;
    int e = beg;
    for (; e + 4 <= end; e += 4) {
        int s0 = col[e], s1 = col[e + 1], s2 = col[e + 2], s3 = col[e + 3];
        VT a0 = *(const VT*)(x + (size_t)s0 * D + off);
        VT a1 = *(const VT*)(x + (size_t)s1 * D + off);
        VT a2 = *(const VT*)(x + (size_t)s2 * D + off);
        VT a3 = *(const VT*)(x + (size_t)s3 * D + off);
        vadd(acc, a0); vadd(acc, a1); vadd(acc, a2); vadd(acc, a3);
    }
    for (; e < end; e++) {
        VT a = *(const VT*)(x + (size_t)col[e] * D + off);
        vadd(acc, a);
    }
    *(VT*)(agg + (size_t)node * D + off) = acc;
}

// ============ fused GEMM: out = leakyrelu([agg|h] @ [Wr|Ws]^T + b) ==========
__global__ __launch_bounds__(256) void gemm_fused_kernel(
    const float* __restrict__ A0, const float* __restrict__ A1,
    const float* __restrict__ B0, const float* __restrict__ B1,
    const float* __restrict__ bias, float* __restrict__ out,
    int N, int d_in, int d_out)
{
    __shared__ float As[16][64];
    __shared__ float Bs[16][64];
    const int tid  = threadIdx.x;
    const int row0 = blockIdx.x * 64;
    const int col0 = blockIdx.y * 64;
    const int tx = tid & 15;
    const int ty = tid >> 4;
    const int lr = tid >> 2;
    const int lk = (tid & 3) << 2;

    float acc[4][4] = {};
    const int Ktot = 2 * d_in;

    for (int k0 = 0; k0 < Ktot; k0 += 16) {
        const int gk = k0 + lk;
        const float* Ap; const float* Bp; int kk;
        if (gk < d_in) { Ap = A0; Bp = B0; kk = gk; }
        else           { Ap = A1; Bp = B1; kk = gk - d_in; }

        const int n = row0 + lr;
        float4 av = make_float4(0.f, 0.f, 0.f, 0.f);
        if (n < NNODES) av = *(const float4*)(Ap + (size_t)n * d_in + kk);
        const float4 bv = *(const float4*)(Bp + (size_t)(col0 + lr) * d_in + kk);

        __syncthreads();
        As[lk + 0][lr] = av.x; As[lk + 1][lr] = av.y;
        As[lk + 2][lr] = av.z; As[lk + 3][lr] = av.w;
        Bs[lk + 0][lr] = bv.x; Bs[lk + 1][lr] = bv.y;
        Bs[lk + 2][lr] = bv.z; Bs[lk + 3][lr] = bv.w;
        __syncthreads();

        #pragma unroll
        for (int k = 0; k < 16; k++) {
            const float4 a = *(const float4*)(&As[k][ty << 2]);
            const float4 b = *(const float4*)(&Bs[k][tx << 2]);
            acc[0][0] += a.x * b.x; acc[0][1] += a.x * b.y;
            acc[0][2] += a.x * b.z; acc[0][3] += a.x * b.w;
            acc[1][0] += a.y * b.x; acc[1][1] += a.y * b.y;
            acc[1][2] += a.y * b.z; acc[1][3] += a.y * b.w;
            acc[2][0] += a.z * b.x; acc[2][1] += a.z * b.y;
            acc[2][2] += a.z * b.z; acc[2][3] += a.z * b.w;
            acc[3][0] += a.w * b.x; acc[3][1] += a.w * b.y;
            acc[3][2] += a.w * b.z; acc[3][3] += a.w * b.w;
        }
    }

    const float4 bb = *(const float4*)(bias + col0 + (tx << 2));
    #pragma unroll
    for (int i = 0; i < 4; i++) {
        const int n = row0 + (ty << 2) + i;
        if (n < NNODES) {
            float4 r;
            r.x = acc[i][0] + bb.x;
            r.y = acc[i][1] + bb.y;
            r.z = acc[i][2] + bb.z;
            r.w = acc[i][3] + bb.w;
            r.x = r.x > 0.f ? r.x : 0.01f * r.x;
            r.y = r.y > 0.f ? r.y : 0.01f * r.y;
            r.z = r.z > 0.f ? r.z : 0.01f * r.z;
            r.w = r.w > 0.f ? r.w : 0.01f * r.w;
            *(float4*)(out + (size_t)n * d_out + col0 + (tx << 2)) = r;
        }
    }
}

extern "C" void kernel_launch(void* const* d_in, const int* in_sizes, int n_in,
                              void* d_out, int out_size, void* d_ws, size_t ws_size,
                              hipStream_t stream) {
    const int N = NNODES;
    const float* x  = (const float*)d_in[0];
    const int*   ei = (const int*)d_in[1];
    const int    E  = in_sizes[1] / 2;
    const int* src = ei;
    const int* dst = ei + E;

    const float* Wr[4] = { (const float*)d_in[2], (const float*)d_in[5],
                           (const float*)d_in[8], (const float*)d_in[11] };
    const float* Ws[4] = { (const float*)d_in[3], (const float*)d_in[6],
                           (const float*)d_in[9], (const float*)d_in[12] };
    const float* bb[4] = { (const float*)d_in[4], (const float*)d_in[7],
                           (const float*)d_in[10], (const float*)d_in[13] };

    float* out  = (float*)d_out;                     // h_final: N x 128
    float* emb  = out + (size_t)N * 128;             // emb:     N x 64

    // workspace layout
    float* agg    = (float*)d_ws;                    // N x 256
    float* hbuf   = agg + (size_t)N * 256;           // N x 256
    int*   rowptr = (int*)(hbuf + (size_t)N * 256);  // N+1
    int*   cnt    = rowptr + (N + 1);                // N
    int*   col    = cnt + N;                         // E
    int*   bsum   = col + E;                         // ceil(N/256)

    const int nb = (N + 255) / 256;                  // 196 scan blocks
    const int eb = (E + 255) / 256;
    const int rowBlocks  = (N + 63) / 64;
    const int nodeBlocks = (N + 3) / 4;

    // ---- CSR build ----
    hipMemsetAsync(cnt, 0, (size_t)N * sizeof(int), stream);
    count_deg<<<eb, 256, 0, stream>>>(dst, cnt, E);
    scan_block<<<nb, 256, 0, stream>>>(cnt, rowptr, bsum, N);
    scan_sums<<<1, 256, 0, stream>>>(bsum, nb);
    scan_add<<<nb, 256, 0, stream>>>(rowptr, bsum, N, E);
    hipMemsetAsync(cnt, 0, (size_t)N * sizeof(int), stream);
    fill_col<<<eb, 256, 0, stream>>>(src, dst, rowptr, cnt, col, E);

    // ---- Layer 0: 128 -> 256, input x, output hbuf ----
    gather_sum<float2, 128><<<nodeBlocks, 256, 0, stream>>>(x, rowptr, col, agg, N);
    gemm_fused_kernel<<<dim3(rowBlocks, 4), 256, 0, stream>>>(
        agg, x, Wr[0], Ws[0], bb[0], hbuf, N, 128, 256);

    // ---- Layer 1: 256 -> 64, input hbuf, output emb ----
    gather_sum<float4, 256><<<nodeBlocks, 256, 0, stream>>>(hbuf, rowptr, col, agg, N);
    gemm_fused_kernel<<<dim3(rowBlocks, 1), 256, 0, stream>>>(
        agg, hbuf, Wr[1], Ws[1], bb[1], emb, N, 256, 64);

    // ---- Layer 2: 64 -> 256, input emb, output hbuf ----
    gather_sum<float, 64><<<nodeBlocks, 256, 0, stream>>>(emb, rowptr, col, agg, N);
    gemm_fused_kernel<<<dim3(rowBlocks, 4), 256, 0, stream>>>(
        agg, emb, Wr[2], Ws[2], bb[2], hbuf, N, 64, 256);

    // ---- Layer 3: 256 -> 128, input hbuf, output out ----
    gather_sum<float4, 256><<<nodeBlocks, 256, 0, stream>>>(hbuf, rowptr, col, agg, N);
    gemm_fused_kernel<<<dim3(rowBlocks, 2), 256, 0, stream>>>(
        agg, hbuf, Wr[3], Ws[3], bb[3], out, N, 256, 128);
}

// Round 3
// 721.961 us; speedup vs baseline: 10.9141x; 1.2552x over previous
//
#include <hip/hip_runtime.h>

#define NNODES 50000

// ======================= CSR build (by destination) =========================
__global__ __launch_bounds__(256) void count_deg(const int* __restrict__ dst,
                                                 int* __restrict__ cnt, int E) {
    int e = blockIdx.x * 256 + threadIdx.x;
    if (e < E) atomicAdd(&cnt[dst[e]], 1);
}

__global__ __launch_bounds__(256) void scan_block(const int* __restrict__ cnt,
                                                  int* __restrict__ rowptr,
                                                  int* __restrict__ bsum, int N) {
    __shared__ int s[256];
    int tid = threadIdx.x;
    int g = blockIdx.x * 256 + tid;
    int v = (g < N) ? cnt[g] : 0;
    s[tid] = v;
    __syncthreads();
    for (int off = 1; off < 256; off <<= 1) {
        int t = (tid >= off) ? s[tid - off] : 0;
        __syncthreads();
        s[tid] += t;
        __syncthreads();
    }
    if (g < N) rowptr[g] = s[tid] - v;       // exclusive
    if (tid == 255) bsum[blockIdx.x] = s[255];
}

__global__ __launch_bounds__(256) void scan_sums(int* __restrict__ bsum, int nb) {
    __shared__ int s[256];
    int tid = threadIdx.x;
    int v = (tid < nb) ? bsum[tid] : 0;
    s[tid] = v;
    __syncthreads();
    for (int off = 1; off < 256; off <<= 1) {
        int t = (tid >= off) ? s[tid - off] : 0;
        __syncthreads();
        s[tid] += t;
        __syncthreads();
    }
    if (tid < nb) bsum[tid] = s[tid] - v;    // exclusive
}

__global__ __launch_bounds__(256) void scan_add(int* __restrict__ rowptr,
                                                const int* __restrict__ bsum,
                                                int N, int E) {
    int g = blockIdx.x * 256 + threadIdx.x;
    if (g < N) rowptr[g] += bsum[blockIdx.x];
    if (g == 0) rowptr[N] = E;
}

__global__ __launch_bounds__(256) void fill_col(const int* __restrict__ src,
                                                const int* __restrict__ dst,
                                                const int* __restrict__ rowptr,
                                                int* __restrict__ cnt,
                                                int* __restrict__ col, int E) {
    int e = blockIdx.x * 256 + threadIdx.x;
    if (e < E) {
        int d = dst[e];
        int p = atomicAdd(&cnt[d], 1);
        col[rowptr[d] + p] = src[e];
    }
}

// ======================= vector helpers =====================================
__device__ inline void vzero(float& a) { a = 0.f; }
__device__ inline void vzero(float2& a) { a.x = a.y = 0.f; }
__device__ inline void vzero(float4& a) { a.x = a.y = a.z = a.w = 0.f; }
__device__ inline void vadd(float& a, const float b) { a += b; }
__device__ inline void vadd(float2& a, const float2 b) { a.x += b.x; a.y += b.y; }
__device__ inline void vadd(float4& a, const float4 b) {
    a.x += b.x; a.y += b.y; a.z += b.z; a.w += b.w;
}
__device__ inline void vlrelu(float& a) { a = a > 0.f ? a : 0.01f * a; }
__device__ inline void vlrelu(float2& a) { vlrelu(a.x); vlrelu(a.y); }
__device__ inline void vlrelu(float4& a) { vlrelu(a.x); vlrelu(a.y); vlrelu(a.z); vlrelu(a.w); }

// ======================= gather-sum (no atomics) ============================
// one wave per node; lane covers sizeof(VT)/4 contiguous features; D = 64*LANEF
template<typename VT, int D>
__global__ __launch_bounds__(256) void gather_sum(
    const float* __restrict__ x, const int* __restrict__ rowptr,
    const int* __restrict__ col, float* __restrict__ agg, int N)
{
    constexpr int LANEF = sizeof(VT) / 4;
    const int wave = threadIdx.x >> 6;
    const int lane = threadIdx.x & 63;
    const int node = blockIdx.x * 4 + wave;
    if (node >= N) return;
    const int beg = rowptr[node], end = rowptr[node + 1];
    VT acc; vzero(acc);
    const size_t off = (size_t)lane * LANEF;
    int e = beg;
    for (; e + 4 <= end; e += 4) {
        int s0 = col[e], s1 = col[e + 1], s2 = col[e + 2], s3 = col[e + 3];
        VT a0 = *(const VT*)(x + (size_t)s0 * D + off);
        VT a1 = *(const VT*)(x + (size_t)s1 * D + off);
        VT a2 = *(const VT*)(x + (size_t)s2 * D + off);
        VT a3 = *(const VT*)(x + (size_t)s3 * D + off);
        vadd(acc, a0); vadd(acc, a1); vadd(acc, a2); vadd(acc, a3);
    }
    for (; e < end; e++) {
        VT a = *(const VT*)(x + (size_t)col[e] * D + off);
        vadd(acc, a);
    }
    *(VT*)(agg + (size_t)node * D + off) = acc;
}

// ============ gather + epilogue: out = lrelu(seg_sum(z[src]) + w + b) =======
// zw is N x 2D (z in cols [0,D), w in cols [D,2D)); out is N x D.
template<typename VT, int D>
__global__ __launch_bounds__(256) void gather_fin(
    const float* __restrict__ zw, const int* __restrict__ rowptr,
    const int* __restrict__ col, const float* __restrict__ bias,
    float* __restrict__ out, int N)
{
    constexpr int LANEF = sizeof(VT) / 4;
    const int wave = threadIdx.x >> 6;
    const int lane = threadIdx.x & 63;
    const int node = blockIdx.x * 4 + wave;
    if (node >= N) return;
    const int beg = rowptr[node], end = rowptr[node + 1];
    const size_t off = (size_t)lane * LANEF;
    VT acc = *(const VT*)(zw + (size_t)node * (2 * D) + D + off);   // w
    VT bb  = *(const VT*)(bias + off);
    vadd(acc, bb);
    int e = beg;
    for (; e + 4 <= end; e += 4) {
        int s0 = col[e], s1 = col[e + 1], s2 = col[e + 2], s3 = col[e + 3];
        VT a0 = *(const VT*)(zw + (size_t)s0 * (2 * D) + off);
        VT a1 = *(const VT*)(zw + (size_t)s1 * (2 * D) + off);
        VT a2 = *(const VT*)(zw + (size_t)s2 * (2 * D) + off);
        VT a3 = *(const VT*)(zw + (size_t)s3 * (2 * D) + off);
        vadd(acc, a0); vadd(acc, a1); vadd(acc, a2); vadd(acc, a3);
    }
    for (; e < end; e++) {
        VT a = *(const VT*)(zw + (size_t)col[e] * (2 * D) + off);
        vadd(acc, a);
    }
    vlrelu(acc);
    *(VT*)(out + (size_t)node * D + off) = acc;
}

// ============ fused GEMM: out = leakyrelu([A0|A1] @ [B0|B1]^T + b) ==========
// 64x64 tile, BK=16, 256 threads, 4x4 acc. LDS leading dim padded to 68
// (write banks become 2-way across the wave -> free; 64 gave 4-way).
__global__ __launch_bounds__(256) void gemm_fused_kernel(
    const float* __restrict__ A0, const float* __restrict__ A1,
    const float* __restrict__ B0, const float* __restrict__ B1,
    const float* __restrict__ bias, float* __restrict__ out,
    int N, int d_in, int d_out)
{
    __shared__ float As[16][68];
    __shared__ float Bs[16][68];
    const int tid  = threadIdx.x;
    const int row0 = blockIdx.x * 64;
    const int col0 = blockIdx.y * 64;
    const int tx = tid & 15;
    const int ty = tid >> 4;
    const int lr = tid >> 2;
    const int lk = (tid & 3) << 2;

    float acc[4][4] = {};
    const int Ktot = 2 * d_in;

    for (int k0 = 0; k0 < Ktot; k0 += 16) {
        const int gk = k0 + lk;
        const float* Ap; const float* Bp; int kk;
        if (gk < d_in) { Ap = A0; Bp = B0; kk = gk; }
        else           { Ap = A1; Bp = B1; kk = gk - d_in; }

        const int n = row0 + lr;
        float4 av = make_float4(0.f, 0.f, 0.f, 0.f);
        if (n < NNODES) av = *(const float4*)(Ap + (size_t)n * d_in + kk);
        const float4 bv = *(const float4*)(Bp + (size_t)(col0 + lr) * d_in + kk);

        __syncthreads();
        As[lk + 0][lr] = av.x; As[lk + 1][lr] = av.y;
        As[lk + 2][lr] = av.z; As[lk + 3][lr] = av.w;
        Bs[lk + 0][lr] = bv.x; Bs[lk + 1][lr] = bv.y;
        Bs[lk + 2][lr] = bv.z; Bs[lk + 3][lr] = bv.w;
        __syncthreads();

        #pragma unroll
        for (int k = 0; k < 16; k++) {
            const float4 a = *(const float4*)(&As[k][ty << 2]);
            const float4 b = *(const float4*)(&Bs[k][tx << 2]);
            acc[0][0] += a.x * b.x; acc[0][1] += a.x * b.y;
            acc[0][2] += a.x * b.z; acc[0][3] += a.x * b.w;
            acc[1][0] += a.y * b.x; acc[1][1] += a.y * b.y;
            acc[1][2] += a.y * b.z; acc[1][3] += a.y * b.w;
            acc[2][0] += a.z * b.x; acc[2][1] += a.z * b.y;
            acc[2][2] += a.z * b.z; acc[2][3] += a.z * b.w;
            acc[3][0] += a.w * b.x; acc[3][1] += a.w * b.y;
            acc[3][2] += a.w * b.z; acc[3][3] += a.w * b.w;
        }
    }

    const float4 bb = *(const float4*)(bias + col0 + (tx << 2));
    #pragma unroll
    for (int i = 0; i < 4; i++) {
        const int n = row0 + (ty << 2) + i;
        if (n < NNODES) {
            float4 r;
            r.x = acc[i][0] + bb.x;
            r.y = acc[i][1] + bb.y;
            r.z = acc[i][2] + bb.z;
            r.w = acc[i][3] + bb.w;
            vlrelu(r);
            *(float4*)(out + (size_t)n * d_out + col0 + (tx << 2)) = r;
        }
    }
}

// ============ pre-GEMM: zw = A @ [Br;Bs]^T  (no bias, no activation) ========
// A: N x d_in.  Br,Bs: d_out x d_in.  zw: N x 2*d_out (z cols first, w cols).
__global__ __launch_bounds__(256) void gemm_pre_kernel(
    const float* __restrict__ A, const float* __restrict__ Br,
    const float* __restrict__ Bs, float* __restrict__ zw,
    int N, int d_in, int d_out)
{
    __shared__ float As[16][68];
    __shared__ float Bt[16][68];
    const int tid  = threadIdx.x;
    const int row0 = blockIdx.x * 64;
    const int col0 = blockIdx.y * 64;   // over 2*d_out; tile never straddles
    const int tx = tid & 15;
    const int ty = tid >> 4;
    const int lr = tid >> 2;
    const int lk = (tid & 3) << 2;

    const int j = col0 + lr;
    const float* Bp = (j < d_out) ? (Br + (size_t)j * d_in)
                                  : (Bs + (size_t)(j - d_out) * d_in);

    float acc[4][4] = {};

    for (int k0 = 0; k0 < d_in; k0 += 16) {
        const int kk = k0 + lk;
        const int n = row0 + lr;
        float4 av = make_float4(0.f, 0.f, 0.f, 0.f);
        if (n < NNODES) av = *(const float4*)(A + (size_t)n * d_in + kk);
        const float4 bv = *(const float4*)(Bp + kk);

        __syncthreads();
        As[lk + 0][lr] = av.x; As[lk + 1][lr] = av.y;
        As[lk + 2][lr] = av.z; As[lk + 3][lr] = av.w;
        Bt[lk + 0][lr] = bv.x; Bt[lk + 1][lr] = bv.y;
        Bt[lk + 2][lr] = bv.z; Bt[lk + 3][lr] = bv.w;
        __syncthreads();

        #pragma unroll
        for (int k = 0; k < 16; k++) {
            const float4 a = *(const float4*)(&As[k][ty << 2]);
            const float4 b = *(const float4*)(&Bt[k][tx << 2]);
            acc[0][0] += a.x * b.x; acc[0][1] += a.x * b.y;
            acc[0][2] += a.x * b.z; acc[0][3] += a.x * b.w;
            acc[1][0] += a.y * b.x; acc[1][1] += a.y * b.y;
            acc[1][2] += a.y * b.z; acc[1][3] += a.y * b.w;
            acc[2][0] += a.z * b.x; acc[2][1] += a.z * b.y;
            acc[2][2] += a.z * b.z; acc[2][3] += a.z * b.w;
            acc[3][0] += a.w * b.x; acc[3][1] += a.w * b.y;
            acc[3][2] += a.w * b.z; acc[3][3] += a.w * b.w;
        }
    }

    const int ldo = 2 * d_out;
    #pragma unroll
    for (int i = 0; i < 4; i++) {
        const int n = row0 + (ty << 2) + i;
        if (n < NNODES) {
            float4 r = make_float4(acc[i][0], acc[i][1], acc[i][2], acc[i][3]);
            *(float4*)(zw + (size_t)n * ldo + col0 + (tx << 2)) = r;
        }
    }
}

extern "C" void kernel_launch(void* const* d_in, const int* in_sizes, int n_in,
                              void* d_out, int out_size, void* d_ws, size_t ws_size,
                              hipStream_t stream) {
    const int N = NNODES;
    const float* x  = (const float*)d_in[0];
    const int*   ei = (const int*)d_in[1];
    const int    E  = in_sizes[1] / 2;
    const int* src = ei;
    const int* dst = ei + E;

    const float* Wr[4] = { (const float*)d_in[2], (const float*)d_in[5],
                           (const float*)d_in[8], (const float*)d_in[11] };
    const float* Ws[4] = { (const float*)d_in[3], (const float*)d_in[6],
                           (const float*)d_in[9], (const float*)d_in[12] };
    const float* bb[4] = { (const float*)d_in[4], (const float*)d_in[7],
                           (const float*)d_in[10], (const float*)d_in[13] };

    float* out  = (float*)d_out;                     // h_final: N x 128
    float* emb  = out + (size_t)N * 128;             // emb:     N x 64

    // workspace layout
    float* agg    = (float*)d_ws;                    // N x 256 (also zw buffer)
    float* hbuf   = agg + (size_t)N * 256;           // N x 256
    int*   rowptr = (int*)(hbuf + (size_t)N * 256);  // N+1
    int*   cnt    = rowptr + (N + 1);                // N
    int*   col    = cnt + N;                         // E
    int*   bsum   = col + E;                         // ceil(N/256)

    const int nb = (N + 255) / 256;
    const int eb = (E + 255) / 256;
    const int rowBlocks  = (N + 63) / 64;            // 782
    const int nodeBlocks = (N + 3) / 4;

    // ---- CSR build ----
    hipMemsetAsync(cnt, 0, (size_t)N * sizeof(int), stream);
    count_deg<<<eb, 256, 0, stream>>>(dst, cnt, E);
    scan_block<<<nb, 256, 0, stream>>>(cnt, rowptr, bsum, N);
    scan_sums<<<1, 256, 0, stream>>>(bsum, nb);
    scan_add<<<nb, 256, 0, stream>>>(rowptr, bsum, N, E);
    hipMemsetAsync(cnt, 0, (size_t)N * sizeof(int), stream);
    fill_col<<<eb, 256, 0, stream>>>(src, dst, rowptr, cnt, col, E);

    // ---- Layer 0 (gather-first): 128 -> 256, input x, output hbuf ----
    gather_sum<float2, 128><<<nodeBlocks, 256, 0, stream>>>(x, rowptr, col, agg, N);
    gemm_fused_kernel<<<dim3(rowBlocks, 4), 256, 0, stream>>>(
        agg, x, Wr[0], Ws[0], bb[0], hbuf, N, 128, 256);

    // ---- Layer 1 (GEMM-first): 256 -> 64, input hbuf, output emb ----
    gemm_pre_kernel<<<dim3(rowBlocks, 2), 256, 0, stream>>>(
        hbuf, Wr[1], Ws[1], agg, N, 256, 64);                 // zw1: N x 128
    gather_fin<float, 64><<<nodeBlocks, 256, 0, stream>>>(
        agg, rowptr, col, bb[1], emb, N);

    // ---- Layer 2 (gather-first): 64 -> 256, input emb, output hbuf ----
    gather_sum<float, 64><<<nodeBlocks, 256, 0, stream>>>(emb, rowptr, col, agg, N);
    gemm_fused_kernel<<<dim3(rowBlocks, 4), 256, 0, stream>>>(
        agg, emb, Wr[2], Ws[2], bb[2], hbuf, N, 64, 256);

    // ---- Layer 3 (GEMM-first): 256 -> 128, input hbuf, output out ----
    gemm_pre_kernel<<<dim3(rowBlocks, 4), 256, 0, stream>>>(
        hbuf, Wr[3], Ws[3], agg, N, 256, 128);                // zw3: N x 256
    gather_fin<float2, 128><<<nodeBlocks, 256, 0, stream>>>(
        agg, rowptr, col, bb[3], out, N);
}

// Round 4
// 561.225 us; speedup vs baseline: 14.0399x; 1.2864x over previous
//
#include <hip/hip_runtime.h>

#define NNODES 50000

typedef __attribute__((ext_vector_type(8))) short bf16x8;
typedef __attribute__((ext_vector_type(4))) float f32x4;

__device__ inline short f2bf(float f) {
    unsigned u = __float_as_uint(f);
    unsigned r = (u + 0x7FFFu + ((u >> 16) & 1u)) >> 16;
    return (short)r;
}

// ======================= CSR build (by destination) =========================
__global__ __launch_bounds__(256) void count_deg(const int* __restrict__ dst,
                                                 int* __restrict__ cnt, int E) {
    int e = blockIdx.x * 256 + threadIdx.x;
    if (e < E) atomicAdd(&cnt[dst[e]], 1);
}

__global__ __launch_bounds__(256) void scan_block(const int* __restrict__ cnt,
                                                  int* __restrict__ rowptr,
                                                  int* __restrict__ bsum, int N) {
    __shared__ int s[256];
    int tid = threadIdx.x;
    int g = blockIdx.x * 256 + tid;
    int v = (g < N) ? cnt[g] : 0;
    s[tid] = v;
    __syncthreads();
    for (int off = 1; off < 256; off <<= 1) {
        int t = (tid >= off) ? s[tid - off] : 0;
        __syncthreads();
        s[tid] += t;
        __syncthreads();
    }
    if (g < N) rowptr[g] = s[tid] - v;
    if (tid == 255) bsum[blockIdx.x] = s[255];
}

__global__ __launch_bounds__(256) void scan_sums(int* __restrict__ bsum, int nb) {
    __shared__ int s[256];
    int tid = threadIdx.x;
    int v = (tid < nb) ? bsum[tid] : 0;
    s[tid] = v;
    __syncthreads();
    for (int off = 1; off < 256; off <<= 1) {
        int t = (tid >= off) ? s[tid - off] : 0;
        __syncthreads();
        s[tid] += t;
        __syncthreads();
    }
    if (tid < nb) bsum[tid] = s[tid] - v;
}

__global__ __launch_bounds__(256) void scan_add(int* __restrict__ rowptr,
                                                const int* __restrict__ bsum,
                                                int N, int E) {
    int g = blockIdx.x * 256 + threadIdx.x;
    if (g < N) rowptr[g] += bsum[blockIdx.x];
    if (g == 0) rowptr[N] = E;
}

__global__ __launch_bounds__(256) void fill_col(const int* __restrict__ src,
                                                const int* __restrict__ dst,
                                                const int* __restrict__ rowptr,
                                                int* __restrict__ cnt,
                                                int* __restrict__ col, int E) {
    int e = blockIdx.x * 256 + threadIdx.x;
    if (e < E) {
        int d = dst[e];
        int p = atomicAdd(&cnt[d], 1);
        col[rowptr[d] + p] = src[e];
    }
}

// ======================= converts ===========================================
__global__ __launch_bounds__(256) void cvt_x(const float* __restrict__ in,
                                             short* __restrict__ out, int n4) {
    int i = blockIdx.x * 256 + threadIdx.x;
    if (i < n4) {
        float4 v = ((const float4*)in)[i];
        short4 s;
        s.x = f2bf(v.x); s.y = f2bf(v.y); s.z = f2bf(v.z); s.w = f2bf(v.w);
        *(short4*)(out + (size_t)i * 4) = s;
    }
}

// 8 weight matrices, hardcoded sizes, concatenated into one bf16 buffer
__global__ __launch_bounds__(256) void cvt_weights(
    const float* __restrict__ p0, const float* __restrict__ p1,
    const float* __restrict__ p2, const float* __restrict__ p3,
    const float* __restrict__ p4, const float* __restrict__ p5,
    const float* __restrict__ p6, const float* __restrict__ p7,
    short* __restrict__ out) {
    int g = blockIdx.x * 256 + threadIdx.x;
    if (g >= 196608) return;
    const float* src; int off;
    if      (g <  32768) { src = p0; off = g; }
    else if (g <  65536) { src = p1; off = g -  32768; }
    else if (g <  81920) { src = p2; off = g -  65536; }
    else if (g <  98304) { src = p3; off = g -  81920; }
    else if (g < 114688) { src = p4; off = g -  98304; }
    else if (g < 131072) { src = p5; off = g - 114688; }
    else if (g < 163840) { src = p6; off = g - 131072; }
    else                 { src = p7; off = g - 163840; }
    out[g] = f2bf(src[off]);
}

// ======================= vector helpers =====================================
__device__ inline void vzero(float& a) { a = 0.f; }
__device__ inline void vzero(float2& a) { a.x = a.y = 0.f; }
__device__ inline void vzero(float4& a) { a.x = a.y = a.z = a.w = 0.f; }
__device__ inline void vadd(float& a, const float b) { a += b; }
__device__ inline void vadd(float2& a, const float2 b) { a.x += b.x; a.y += b.y; }
__device__ inline void vadd(float4& a, const float4 b) {
    a.x += b.x; a.y += b.y; a.z += b.z; a.w += b.w;
}
__device__ inline void vlrelu(float& a) { a = a > 0.f ? a : 0.01f * a; }
__device__ inline void vlrelu(float2& a) { vlrelu(a.x); vlrelu(a.y); }
__device__ inline void vlrelu(float4& a) { vlrelu(a.x); vlrelu(a.y); vlrelu(a.z); vlrelu(a.w); }
__device__ inline void store_bf(short* p, float v) { *p = f2bf(v); }
__device__ inline void store_bf(short* p, float2 v) {
    short2 s; s.x = f2bf(v.x); s.y = f2bf(v.y); *(short2*)p = s;
}
__device__ inline void store_bf(short* p, float4 v) {
    short4 s; s.x = f2bf(v.x); s.y = f2bf(v.y); s.z = f2bf(v.z); s.w = f2bf(v.w);
    *(short4*)p = s;
}

// ============ gather-sum: aggbf = bf16(seg_sum(x[src]))  (fp32 acc) =========
template<typename VT, int D>
__global__ __launch_bounds__(256) void gather_sum_bf(
    const float* __restrict__ x, const int* __restrict__ rowptr,
    const int* __restrict__ col, short* __restrict__ aggbf, int N)
{
    constexpr int LANEF = sizeof(VT) / 4;
    const int wave = threadIdx.x >> 6;
    const int lane = threadIdx.x & 63;
    const int node = blockIdx.x * 4 + wave;
    if (node >= N) return;
    const int beg = rowptr[node], end = rowptr[node + 1];
    VT acc; vzero(acc);
    const size_t off = (size_t)lane * LANEF;
    int e = beg;
    for (; e + 4 <= end; e += 4) {
        int s0 = col[e], s1 = col[e + 1], s2 = col[e + 2], s3 = col[e + 3];
        VT a0 = *(const VT*)(x + (size_t)s0 * D + off);
        VT a1 = *(const VT*)(x + (size_t)s1 * D + off);
        VT a2 = *(const VT*)(x + (size_t)s2 * D + off);
        VT a3 = *(const VT*)(x + (size_t)s3 * D + off);
        vadd(acc, a0); vadd(acc, a1); vadd(acc, a2); vadd(acc, a3);
    }
    for (; e < end; e++) {
        VT a = *(const VT*)(x + (size_t)col[e] * D + off);
        vadd(acc, a);
    }
    store_bf(aggbf + (size_t)node * D + off, acc);
}

// ==== gather + epilogue: out = lrelu(seg_sum(z[src]) + w + b); optional bf16 copy
// zw is N x 2D fp32 (z cols [0,D), w cols [D,2D)); out fp32 N x D.
template<typename VT, int D>
__global__ __launch_bounds__(256) void gather_fin(
    const float* __restrict__ zw, const int* __restrict__ rowptr,
    const int* __restrict__ col, const float* __restrict__ bias,
    float* __restrict__ out, short* __restrict__ out_bf, int N)
{
    constexpr int LANEF = sizeof(VT) / 4;
    const int wave = threadIdx.x >> 6;
    const int lane = threadIdx.x & 63;
    const int node = blockIdx.x * 4 + wave;
    if (node >= N) return;
    const int beg = rowptr[node], end = rowptr[node + 1];
    const size_t off = (size_t)lane * LANEF;
    VT acc = *(const VT*)(zw + (size_t)node * (2 * D) + D + off);
    VT bb  = *(const VT*)(bias + off);
    vadd(acc, bb);
    int e = beg;
    for (; e + 4 <= end; e += 4) {
        int s0 = col[e], s1 = col[e + 1], s2 = col[e + 2], s3 = col[e + 3];
        VT a0 = *(const VT*)(zw + (size_t)s0 * (2 * D) + off);
        VT a1 = *(const VT*)(zw + (size_t)s1 * (2 * D) + off);
        VT a2 = *(const VT*)(zw + (size_t)s2 * (2 * D) + off);
        VT a3 = *(const VT*)(zw + (size_t)s3 * (2 * D) + off);
        vadd(acc, a0); vadd(acc, a1); vadd(acc, a2); vadd(acc, a3);
    }
    for (; e < end; e++) {
        VT a = *(const VT*)(zw + (size_t)col[e] * (2 * D) + off);
        vadd(acc, a);
    }
    vlrelu(acc);
    *(VT*)(out + (size_t)node * D + off) = acc;
    if (out_bf) store_bf(out_bf + (size_t)node * D + off, acc);
}

// ======================= MFMA GEMM ==========================================
// FUSED: out_bf16 = lrelu([A0|A1] @ [B0|B1]^T + bias), Ktot=2*dk, Ncols=d_out
// PRE:   out_f32  = A0 @ [B0;B1]^T (cols 0..d_out-1 from B0), Ktot=dk, Ncols=2*d_out
// Tile 128x128, BK=32, 4 waves in 2x2 (each 64x64 = 4x4 frags of 16x16x32).
// LDS stride 40 shorts (80B, 16B-aligned; frag reads <=2-way bank alias = free).
template<bool FUSED>
__global__ __launch_bounds__(256) void gemm_mfma(
    const short* __restrict__ A0, const short* __restrict__ A1,
    const short* __restrict__ B0, const short* __restrict__ B1,
    const float* __restrict__ bias, float* __restrict__ outF,
    short* __restrict__ outH, int N, int dk, int d_out)
{
    __shared__ short As[128 * 40];
    __shared__ short Bs[128 * 40];
    const int tid  = threadIdx.x;
    const int row0 = blockIdx.x * 128;
    const int col0 = blockIdx.y * 128;
    const int w    = tid >> 6;
    const int lane = tid & 63;
    const int wr   = (w & 1) << 6;
    const int wc   = (w >> 1) << 6;
    const int m16  = lane & 15;
    const int quad = lane >> 4;

    const int Ktot  = FUSED ? 2 * dk : dk;
    const int Ncols = FUSED ? d_out : 2 * d_out;

    f32x4 acc[4][4] = {};

    for (int kk = 0; kk < Ktot; kk += 32) {
        const short* Ap; const short* Bp0 = B0; int ko;
        if (FUSED) {
            if (kk < dk) { Ap = A0; Bp0 = B0; ko = kk; }
            else         { Ap = A1; Bp0 = B1; ko = kk - dk; }
        } else { Ap = A0; ko = kk; }

        int4 aval[2]; int4 bval[2]; int lidx[2];
        #pragma unroll
        for (int it = 0; it < 2; it++) {
            int idx = tid + it * 256;        // 0..511
            int r = idx >> 2, seg = idx & 3; // 128 rows x 4 x 16B
            int ar = row0 + r; ar = ar < N ? ar : N - 1;
            aval[it] = *(const int4*)(Ap + (size_t)ar * dk + ko + seg * 8);
            int j = col0 + r;
            const short* bp;
            if (FUSED) bp = Bp0 + (size_t)j * dk;
            else bp = (j < d_out) ? (B0 + (size_t)j * dk)
                                  : (B1 + (size_t)(j - d_out) * dk);
            bval[it] = *(const int4*)(bp + ko + seg * 8);
            lidx[it] = r * 40 + seg * 8;
        }
        __syncthreads();
        #pragma unroll
        for (int it = 0; it < 2; it++) {
            *(int4*)(As + lidx[it]) = aval[it];
            *(int4*)(Bs + lidx[it]) = bval[it];
        }
        __syncthreads();

        bf16x8 af[4];
        #pragma unroll
        for (int i = 0; i < 4; i++)
            af[i] = *(const bf16x8*)(As + (wr + i * 16 + m16) * 40 + quad * 8);
        #pragma unroll
        for (int j = 0; j < 4; j++) {
            bf16x8 bfr = *(const bf16x8*)(Bs + (wc + j * 16 + m16) * 40 + quad * 8);
            #pragma unroll
            for (int i = 0; i < 4; i++)
                acc[i][j] = __builtin_amdgcn_mfma_f32_16x16x32_bf16(
                    af[i], bfr, acc[i][j], 0, 0, 0);
        }
    }

    // epilogue: C/D layout col=lane&15, row=quad*4+reg
    #pragma unroll
    for (int j = 0; j < 4; j++) {
        const int colg = col0 + wc + j * 16 + m16;
        float bv = FUSED ? bias[colg] : 0.f;
        #pragma unroll
        for (int i = 0; i < 4; i++) {
            #pragma unroll
            for (int r = 0; r < 4; r++) {
                int row = row0 + wr + i * 16 + quad * 4 + r;
                if (row < N) {
                    float v = acc[i][j][r];
                    if (FUSED) {
                        v += bv;
                        v = v > 0.f ? v : 0.01f * v;
                        outH[(size_t)row * Ncols + colg] = f2bf(v);
                    } else {
                        outF[(size_t)row * Ncols + colg] = v;
                    }
                }
            }
        }
    }
}

extern "C" void kernel_launch(void* const* d_in, const int* in_sizes, int n_in,
                              void* d_out, int out_size, void* d_ws, size_t ws_size,
                              hipStream_t stream) {
    const int N = NNODES;
    const float* x  = (const float*)d_in[0];
    const int*   ei = (const int*)d_in[1];
    const int    E  = in_sizes[1] / 2;
    const int* src = ei;
    const int* dst = ei + E;

    const float* Wr[4] = { (const float*)d_in[2], (const float*)d_in[5],
                           (const float*)d_in[8], (const float*)d_in[11] };
    const float* Ws[4] = { (const float*)d_in[3], (const float*)d_in[6],
                           (const float*)d_in[9], (const float*)d_in[12] };
    const float* bb[4] = { (const float*)d_in[4], (const float*)d_in[7],
                           (const float*)d_in[10], (const float*)d_in[13] };

    float* out  = (float*)d_out;                     // h_final: N x 128
    float* emb  = out + (size_t)N * 128;             // emb:     N x 64

    // workspace layout (aggbf overlays zw; lifetimes verified disjoint)
    float* zw     = (float*)d_ws;                    // N x 256 fp32
    short* aggbf  = (short*)zw;                      // N x 128 bf16 (overlay)
    short* xbf    = (short*)(zw + (size_t)N * 256);  // N x 128 bf16
    short* h1bf   = xbf + (size_t)N * 128;           // N x 256 bf16 (also h3bf)
    short* embbf  = h1bf + (size_t)N * 256;          // N x 64 bf16
    short* wbf    = embbf + (size_t)N * 64;          // 196608 bf16
    int*   rowptr = (int*)(wbf + 196608);            // N+1
    int*   cnt    = rowptr + (N + 1);                // N
    int*   col    = cnt + N;                         // E
    int*   bsum   = col + E;                         // ceil(N/256)

    const short* wr0 = wbf;           const short* ws0 = wbf + 32768;
    const short* wr1 = wbf + 65536;   const short* ws1 = wbf + 81920;
    const short* wr2 = wbf + 98304;   const short* ws2 = wbf + 114688;
    const short* wr3 = wbf + 131072;  const short* ws3 = wbf + 163840;

    const int nb = (N + 255) / 256;
    const int eb = (E + 255) / 256;
    const int gemmRB   = (N + 127) / 128;            // 391
    const int nodeBlocks = (N + 3) / 4;

    // ---- CSR build + converts ----
    hipMemsetAsync(cnt, 0, (size_t)N * sizeof(int), stream);
    count_deg<<<eb, 256, 0, stream>>>(dst, cnt, E);
    scan_block<<<nb, 256, 0, stream>>>(cnt, rowptr, bsum, N);
    scan_sums<<<1, 256, 0, stream>>>(bsum, nb);
    scan_add<<<nb, 256, 0, stream>>>(rowptr, bsum, N, E);
    hipMemsetAsync(cnt, 0, (size_t)N * sizeof(int), stream);
    fill_col<<<eb, 256, 0, stream>>>(src, dst, rowptr, cnt, col, E);
    cvt_x<<<(N * 128 / 4 + 255) / 256, 256, 0, stream>>>(x, xbf, N * 128 / 4);
    cvt_weights<<<(196608 + 255) / 256, 256, 0, stream>>>(
        Wr[0], Ws[0], Wr[1], Ws[1], Wr[2], Ws[2], Wr[3], Ws[3], wbf);

    // ---- Layer 0 (gather-first): 128 -> 256 ----
    gather_sum_bf<float2, 128><<<nodeBlocks, 256, 0, stream>>>(x, rowptr, col, aggbf, N);
    gemm_mfma<true><<<dim3(gemmRB, 2), 256, 0, stream>>>(
        aggbf, xbf, wr0, ws0, bb[0], nullptr, h1bf, N, 128, 256);

    // ---- Layer 1 (GEMM-first): 256 -> 64 ----
    gemm_mfma<false><<<dim3(gemmRB, 1), 256, 0, stream>>>(
        h1bf, nullptr, wr1, ws1, nullptr, zw, nullptr, N, 256, 64);
    gather_fin<float, 64><<<nodeBlocks, 256, 0, stream>>>(
        zw, rowptr, col, bb[1], emb, embbf, N);

    // ---- Layer 2 (gather-first): 64 -> 256 ----
    gather_sum_bf<float, 64><<<nodeBlocks, 256, 0, stream>>>(emb, rowptr, col, aggbf, N);
    gemm_mfma<true><<<dim3(gemmRB, 2), 256, 0, stream>>>(
        aggbf, embbf, wr2, ws2, bb[2], nullptr, h1bf /*h3bf*/, N, 64, 256);

    // ---- Layer 3 (GEMM-first): 256 -> 128 ----
    gemm_mfma<false><<<dim3(gemmRB, 2), 256, 0, stream>>>(
        h1bf /*h3bf*/, nullptr, wr3, ws3, nullptr, zw, nullptr, N, 256, 128);
    gather_fin<float2, 128><<<nodeBlocks, 256, 0, stream>>>(
        zw, rowptr, col, bb[3], out, nullptr, N);
}

// Round 5
// 469.367 us; speedup vs baseline: 16.7876x; 1.1957x over previous
//
#include <hip/hip_runtime.h>

#define NNODES 50000

typedef __attribute__((ext_vector_type(8))) short bf16x8;
typedef __attribute__((ext_vector_type(4))) float f32x4;

__device__ inline short f2bf(float f) {
    unsigned u = __float_as_uint(f);
    unsigned r = (u + 0x7FFFu + ((u >> 16) & 1u)) >> 16;
    return (short)r;
}
__device__ inline float bf2f(short s) {
    return __uint_as_float(((unsigned)(unsigned short)s) << 16);
}
__device__ inline float2 bfp2f(int p) {   // packed pair: low short = elem 0
    float2 f;
    f.x = __uint_as_float((unsigned)p << 16);
    f.y = __uint_as_float((unsigned)p & 0xFFFF0000u);
    return f;
}

// ======================= CSR build (by destination) =========================
__global__ __launch_bounds__(256) void count_deg(const int* __restrict__ dst,
                                                 int* __restrict__ cnt, int E) {
    int e = blockIdx.x * 256 + threadIdx.x;
    if (e < E) atomicAdd(&cnt[dst[e]], 1);
}

__global__ __launch_bounds__(256) void scan_block(const int* __restrict__ cnt,
                                                  int* __restrict__ rowptr,
                                                  int* __restrict__ bsum, int N) {
    __shared__ int s[256];
    int tid = threadIdx.x;
    int g = blockIdx.x * 256 + tid;
    int v = (g < N) ? cnt[g] : 0;
    s[tid] = v;
    __syncthreads();
    for (int off = 1; off < 256; off <<= 1) {
        int t = (tid >= off) ? s[tid - off] : 0;
        __syncthreads();
        s[tid] += t;
        __syncthreads();
    }
    if (g < N) rowptr[g] = s[tid] - v;
    if (tid == 255) bsum[blockIdx.x] = s[255];
}

__global__ __launch_bounds__(256) void scan_sums(int* __restrict__ bsum, int nb) {
    __shared__ int s[256];
    int tid = threadIdx.x;
    int v = (tid < nb) ? bsum[tid] : 0;
    s[tid] = v;
    __syncthreads();
    for (int off = 1; off < 256; off <<= 1) {
        int t = (tid >= off) ? s[tid - off] : 0;
        __syncthreads();
        s[tid] += t;
        __syncthreads();
    }
    if (tid < nb) bsum[tid] = s[tid] - v;
}

__global__ __launch_bounds__(256) void scan_add(int* __restrict__ rowptr,
                                                const int* __restrict__ bsum,
                                                int N, int E) {
    int g = blockIdx.x * 256 + threadIdx.x;
    if (g < N) rowptr[g] += bsum[blockIdx.x];
    if (g == 0) rowptr[N] = E;
}

__global__ __launch_bounds__(256) void fill_col(const int* __restrict__ src,
                                                const int* __restrict__ dst,
                                                const int* __restrict__ rowptr,
                                                int* __restrict__ cnt,
                                                int* __restrict__ col, int E) {
    int e = blockIdx.x * 256 + threadIdx.x;
    if (e < E) {
        int d = dst[e];
        int p = atomicAdd(&cnt[d], 1);
        col[rowptr[d] + p] = src[e];
    }
}

// ======================= converts ===========================================
__global__ __launch_bounds__(256) void cvt_x(const float* __restrict__ in,
                                             short* __restrict__ out, int n4) {
    int i = blockIdx.x * 256 + threadIdx.x;
    if (i < n4) {
        float4 v = ((const float4*)in)[i];
        short4 s;
        s.x = f2bf(v.x); s.y = f2bf(v.y); s.z = f2bf(v.z); s.w = f2bf(v.w);
        *(short4*)(out + (size_t)i * 4) = s;
    }
}

__global__ __launch_bounds__(256) void cvt_weights(
    const float* __restrict__ p0, const float* __restrict__ p1,
    const float* __restrict__ p2, const float* __restrict__ p3,
    const float* __restrict__ p4, const float* __restrict__ p5,
    const float* __restrict__ p6, const float* __restrict__ p7,
    short* __restrict__ out) {
    int g = blockIdx.x * 256 + threadIdx.x;
    if (g >= 196608) return;
    const float* src; int off;
    if      (g <  32768) { src = p0; off = g; }
    else if (g <  65536) { src = p1; off = g -  32768; }
    else if (g <  81920) { src = p2; off = g -  65536; }
    else if (g <  98304) { src = p3; off = g -  81920; }
    else if (g < 114688) { src = p4; off = g -  98304; }
    else if (g < 131072) { src = p5; off = g - 114688; }
    else if (g < 163840) { src = p6; off = g - 131072; }
    else                 { src = p7; off = g - 163840; }
    out[g] = f2bf(src[off]);
}

// ============ gather-sum over bf16 rows -> bf16 agg (fp32 accumulate) =======
// D=128: lane holds 2 feats (int load); D=64: lane holds 1 feat (short load).
template<int D>
__global__ __launch_bounds__(256) void gather_sum_bf(
    const short* __restrict__ xbf, const int* __restrict__ rowptr,
    const int* __restrict__ col, short* __restrict__ aggbf, int N)
{
    const int wave = threadIdx.x >> 6;
    const int lane = threadIdx.x & 63;
    const int node = blockIdx.x * 4 + wave;
    if (node >= N) return;
    const int beg = rowptr[node], end = rowptr[node + 1];
    int e = beg;
    if (D == 128) {
        float2 acc = make_float2(0.f, 0.f);
        for (; e + 4 <= end; e += 4) {
            int s0 = col[e], s1 = col[e+1], s2 = col[e+2], s3 = col[e+3];
            int p0 = ((const int*)(xbf + (size_t)s0 * D))[lane];
            int p1 = ((const int*)(xbf + (size_t)s1 * D))[lane];
            int p2 = ((const int*)(xbf + (size_t)s2 * D))[lane];
            int p3 = ((const int*)(xbf + (size_t)s3 * D))[lane];
            float2 f0 = bfp2f(p0), f1 = bfp2f(p1), f2 = bfp2f(p2), f3 = bfp2f(p3);
            acc.x += f0.x + f1.x + f2.x + f3.x;
            acc.y += f0.y + f1.y + f2.y + f3.y;
        }
        for (; e < end; e++) {
            float2 f = bfp2f(((const int*)(xbf + (size_t)col[e] * D))[lane]);
            acc.x += f.x; acc.y += f.y;
        }
        short2 s; s.x = f2bf(acc.x); s.y = f2bf(acc.y);
        *(short2*)(aggbf + (size_t)node * D + lane * 2) = s;
    } else {
        float acc = 0.f;
        for (; e + 4 <= end; e += 4) {
            int s0 = col[e], s1 = col[e+1], s2 = col[e+2], s3 = col[e+3];
            acc += bf2f(xbf[(size_t)s0 * D + lane]) + bf2f(xbf[(size_t)s1 * D + lane])
                 + bf2f(xbf[(size_t)s2 * D + lane]) + bf2f(xbf[(size_t)s3 * D + lane]);
        }
        for (; e < end; e++) acc += bf2f(xbf[(size_t)col[e] * D + lane]);
        aggbf[(size_t)node * D + lane] = f2bf(acc);
    }
}

// ==== gather + epilogue: out = lrelu(seg_sum(z[src]) + w + b), zw bf16 ======
// zw: N x 2D bf16 (z cols [0,D), w cols [D,2D)). out fp32 N x D (+opt bf16).
template<int D>
__global__ __launch_bounds__(256) void gather_fin(
    const short* __restrict__ zw, const int* __restrict__ rowptr,
    const int* __restrict__ col, const float* __restrict__ bias,
    float* __restrict__ out, short* __restrict__ out_bf, int N)
{
    const int wave = threadIdx.x >> 6;
    const int lane = threadIdx.x & 63;
    const int node = blockIdx.x * 4 + wave;
    if (node >= N) return;
    const int beg = rowptr[node], end = rowptr[node + 1];
    int e = beg;
    if (D == 128) {
        float2 acc = bfp2f(((const int*)(zw + (size_t)node * 256 + 128))[lane]);
        float2 bb = *(const float2*)(bias + lane * 2);
        acc.x += bb.x; acc.y += bb.y;
        for (; e + 4 <= end; e += 4) {
            int s0 = col[e], s1 = col[e+1], s2 = col[e+2], s3 = col[e+3];
            float2 f0 = bfp2f(((const int*)(zw + (size_t)s0 * 256))[lane]);
            float2 f1 = bfp2f(((const int*)(zw + (size_t)s1 * 256))[lane]);
            float2 f2 = bfp2f(((const int*)(zw + (size_t)s2 * 256))[lane]);
            float2 f3 = bfp2f(((const int*)(zw + (size_t)s3 * 256))[lane]);
            acc.x += f0.x + f1.x + f2.x + f3.x;
            acc.y += f0.y + f1.y + f2.y + f3.y;
        }
        for (; e < end; e++) {
            float2 f = bfp2f(((const int*)(zw + (size_t)col[e] * 256))[lane]);
            acc.x += f.x; acc.y += f.y;
        }
        acc.x = acc.x > 0.f ? acc.x : 0.01f * acc.x;
        acc.y = acc.y > 0.f ? acc.y : 0.01f * acc.y;
        *(float2*)(out + (size_t)node * D + lane * 2) = acc;
        if (out_bf) {
            short2 s; s.x = f2bf(acc.x); s.y = f2bf(acc.y);
            *(short2*)(out_bf + (size_t)node * D + lane * 2) = s;
        }
    } else {
        float acc = bf2f(zw[(size_t)node * 128 + 64 + lane]) + bias[lane];
        for (; e + 4 <= end; e += 4) {
            int s0 = col[e], s1 = col[e+1], s2 = col[e+2], s3 = col[e+3];
            acc += bf2f(zw[(size_t)s0 * 128 + lane]) + bf2f(zw[(size_t)s1 * 128 + lane])
                 + bf2f(zw[(size_t)s2 * 128 + lane]) + bf2f(zw[(size_t)s3 * 128 + lane]);
        }
        for (; e < end; e++) acc += bf2f(zw[(size_t)col[e] * 128 + lane]);
        acc = acc > 0.f ? acc : 0.01f * acc;
        out[(size_t)node * D + lane] = acc;
        if (out_bf) out_bf[(size_t)node * D + lane] = f2bf(acc);
    }
}

// ======================= MFMA GEMM (pipelined, coalesced bf16 epilogue) =====
// FUSED: outH = bf16(lrelu([A0|A1] @ [B0|B1]^T + bias)),  Ktot=2*dk, Ncols=d_out
// PRE:   outH = bf16(A0 @ [B0;B1]^T),                     Ktot=dk,  Ncols=2*d_out
// Tile 128x128, BK=32, 4 waves 2x2 (each 64x64 via 4x4 frags of 16x16x32).
// LDS: double-buffered stage (2 x (A+B) x 128x40 shorts = 40960B), reused for
// per-wave epilogue transpose (4 x 64x72 shorts = 36864B).
template<bool FUSED>
__global__ __launch_bounds__(256) void gemm_mfma(
    const short* __restrict__ A0, const short* __restrict__ A1,
    const short* __restrict__ B0, const short* __restrict__ B1,
    const float* __restrict__ bias, short* __restrict__ outH,
    int N, int dk, int d_out)
{
    __shared__ short smem[20480];          // 40960 bytes
    const int tid  = threadIdx.x;
    const int row0 = blockIdx.x * 128;
    const int col0 = blockIdx.y * 128;
    const int w    = tid >> 6;
    const int lane = tid & 63;
    const int wr   = (w & 1) << 6;
    const int wc   = (w >> 1) << 6;
    const int m16  = lane & 15;
    const int quad = lane >> 4;

    const int Ktot  = FUSED ? 2 * dk : dk;
    const int Ncols = FUSED ? d_out : 2 * d_out;
    const int iters = Ktot >> 5;

    const int lr  = tid >> 2;              // 0..63 (+64 on second it)
    const int lsg = tid & 3;               // 16B segment within BK row

    f32x4 acc[4][4] = {};
    int4 aval[2], bval[2];

    auto load_tile = [&](int kk) {
        const short* Ap; const short* Bp0 = B0; int ko;
        if (FUSED) {
            if (kk < dk) { Ap = A0; Bp0 = B0; ko = kk; }
            else         { Ap = A1; Bp0 = B1; ko = kk - dk; }
        } else { Ap = A0; ko = kk; }
        #pragma unroll
        for (int it = 0; it < 2; it++) {
            int r = lr + it * 64;
            int ar = row0 + r; ar = ar < N ? ar : N - 1;
            aval[it] = *(const int4*)(Ap + (size_t)ar * dk + ko + lsg * 8);
            int j = col0 + r;
            const short* bp;
            if (FUSED) bp = Bp0 + (size_t)j * dk;
            else bp = (j < d_out) ? (B0 + (size_t)j * dk)
                                  : (B1 + (size_t)(j - d_out) * dk);
            bval[it] = *(const int4*)(bp + ko + lsg * 8);
        }
    };
    auto store_tile = [&](int buf) {
        short* Ab = smem + buf * 10240;
        short* Bb = Ab + 5120;
        #pragma unroll
        for (int it = 0; it < 2; it++) {
            int r = lr + it * 64;
            *(int4*)(Ab + r * 40 + lsg * 8) = aval[it];
            *(int4*)(Bb + r * 40 + lsg * 8) = bval[it];
        }
    };

    load_tile(0);
    store_tile(0);
    __syncthreads();

    for (int k = 0; k < iters; k++) {
        const int cur = k & 1;
        const bool more = (k + 1 < iters);
        if (more) load_tile((k + 1) << 5);

        const short* Ab = smem + cur * 10240;
        const short* Bb = Ab + 5120;
        bf16x8 af[4];
        #pragma unroll
        for (int i = 0; i < 4; i++)
            af[i] = *(const bf16x8*)(Ab + (wr + i * 16 + m16) * 40 + quad * 8);
        #pragma unroll
        for (int j = 0; j < 4; j++) {
            bf16x8 bfr = *(const bf16x8*)(Bb + (wc + j * 16 + m16) * 40 + quad * 8);
            #pragma unroll
            for (int i = 0; i < 4; i++)
                acc[i][j] = __builtin_amdgcn_mfma_f32_16x16x32_bf16(
                    af[i], bfr, acc[i][j], 0, 0, 0);
        }
        if (more) store_tile((k + 1) & 1);
        __syncthreads();
    }

    // ---- epilogue: per-wave LDS transpose -> full-line bf16 stores ----
    short* ep = smem + w * 4608;           // 64 rows x 72 shorts (144B, 16B-mult)
    #pragma unroll
    for (int j = 0; j < 4; j++) {
        const int colg = col0 + wc + j * 16 + m16;
        const float bv = FUSED ? bias[colg] : 0.f;
        #pragma unroll
        for (int i = 0; i < 4; i++) {
            #pragma unroll
            for (int r = 0; r < 4; r++) {
                float v = acc[i][j][r];
                if (FUSED) { v += bv; v = v > 0.f ? v : 0.01f * v; }
                ep[(i * 16 + quad * 4 + r) * 72 + j * 16 + m16] = f2bf(v);
            }
        }
    }
    __syncthreads();
    const int r8  = lane >> 3;
    const int seg = lane & 7;
    #pragma unroll
    for (int rb = 0; rb < 8; rb++) {
        const int lrow = rb * 8 + r8;
        int4 vv = *(const int4*)(ep + lrow * 72 + seg * 8);
        const int grow = row0 + wr + lrow;
        if (grow < N)
            *(int4*)(outH + (size_t)grow * Ncols + col0 + wc + seg * 8) = vv;
    }
}

extern "C" void kernel_launch(void* const* d_in, const int* in_sizes, int n_in,
                              void* d_out, int out_size, void* d_ws, size_t ws_size,
                              hipStream_t stream) {
    const int N = NNODES;
    const float* x  = (const float*)d_in[0];
    const int*   ei = (const int*)d_in[1];
    const int    E  = in_sizes[1] / 2;
    const int* src = ei;
    const int* dst = ei + E;

    const float* Wr[4] = { (const float*)d_in[2], (const float*)d_in[5],
                           (const float*)d_in[8], (const float*)d_in[11] };
    const float* Ws[4] = { (const float*)d_in[3], (const float*)d_in[6],
                           (const float*)d_in[9], (const float*)d_in[12] };
    const float* bb[4] = { (const float*)d_in[4], (const float*)d_in[7],
                           (const float*)d_in[10], (const float*)d_in[13] };

    float* out  = (float*)d_out;                     // h_final: N x 128 fp32
    float* emb  = out + (size_t)N * 128;             // emb:     N x 64 fp32

    // workspace layout (all bf16 activations; <=100 MB total)
    short* zwbf   = (short*)d_ws;                    // N x 256 bf16 (z|w)
    short* aggbf  = zwbf + (size_t)N * 256;          // N x 256 bf16
    short* xbf    = aggbf + (size_t)N * 256;         // N x 128 bf16
    short* h1bf   = xbf + (size_t)N * 128;           // N x 256 bf16 (also h3)
    short* embbf  = h1bf + (size_t)N * 256;          // N x 64 bf16
    short* wbf    = embbf + (size_t)N * 64;          // 196608 bf16 weights
    int*   rowptr = (int*)(wbf + 196608);            // N+1
    int*   cnt    = rowptr + (N + 1);                // N
    int*   col    = cnt + N;                         // E
    int*   bsum   = col + E;                         // ceil(N/256)

    const short* wr0 = wbf;           const short* ws0 = wbf + 32768;
    const short* wr1 = wbf + 65536;   const short* ws1 = wbf + 81920;
    const short* wr2 = wbf + 98304;   const short* ws2 = wbf + 114688;
    const short* wr3 = wbf + 131072;  const short* ws3 = wbf + 163840;

    const int nb = (N + 255) / 256;
    const int eb = (E + 255) / 256;
    const int gemmRB = (N + 127) / 128;              // 391
    const int nodeBlocks = (N + 3) / 4;

    // ---- CSR build + converts ----
    hipMemsetAsync(cnt, 0, (size_t)N * sizeof(int), stream);
    count_deg<<<eb, 256, 0, stream>>>(dst, cnt, E);
    scan_block<<<nb, 256, 0, stream>>>(cnt, rowptr, bsum, N);
    scan_sums<<<1, 256, 0, stream>>>(bsum, nb);
    scan_add<<<nb, 256, 0, stream>>>(rowptr, bsum, N, E);
    hipMemsetAsync(cnt, 0, (size_t)N * sizeof(int), stream);
    fill_col<<<eb, 256, 0, stream>>>(src, dst, rowptr, cnt, col, E);
    cvt_x<<<(N * 128 / 4 + 255) / 256, 256, 0, stream>>>(x, xbf, N * 128 / 4);
    cvt_weights<<<(196608 + 255) / 256, 256, 0, stream>>>(
        Wr[0], Ws[0], Wr[1], Ws[1], Wr[2], Ws[2], Wr[3], Ws[3], wbf);

    // ---- Layer 0 (gather-first): 128 -> 256 ----
    gather_sum_bf<128><<<nodeBlocks, 256, 0, stream>>>(xbf, rowptr, col, aggbf, N);
    gemm_mfma<true><<<dim3(gemmRB, 2), 256, 0, stream>>>(
        aggbf, xbf, wr0, ws0, bb[0], h1bf, N, 128, 256);

    // ---- Layer 1 (GEMM-first): 256 -> 64 ----
    gemm_mfma<false><<<dim3(gemmRB, 1), 256, 0, stream>>>(
        h1bf, nullptr, wr1, ws1, nullptr, zwbf, N, 256, 64);   // zw1: N x 128
    gather_fin<64><<<nodeBlocks, 256, 0, stream>>>(
        zwbf, rowptr, col, bb[1], emb, embbf, N);

    // ---- Layer 2 (gather-first): 64 -> 256 ----
    gather_sum_bf<64><<<nodeBlocks, 256, 0, stream>>>(embbf, rowptr, col, aggbf, N);
    gemm_mfma<true><<<dim3(gemmRB, 2), 256, 0, stream>>>(
        aggbf, embbf, wr2, ws2, bb[2], h1bf /*h3bf*/, N, 64, 256);

    // ---- Layer 3 (GEMM-first): 256 -> 128 ----
    gemm_mfma<false><<<dim3(gemmRB, 2), 256, 0, stream>>>(
        h1bf /*h3bf*/, nullptr, wr3, ws3, nullptr, zwbf, N, 256, 128); // N x 256
    gather_fin<128><<<nodeBlocks, 256, 0, stream>>>(
        zwbf, rowptr, col, bb[3], out, nullptr, N);
}

// Round 6
// 427.011 us; speedup vs baseline: 18.4528x; 1.0992x over previous
//
#include <hip/hip_runtime.h>

#define NNODES 50000

typedef __attribute__((ext_vector_type(8))) short bf16x8;
typedef __attribute__((ext_vector_type(4))) float f32x4;

__device__ inline short f2bf(float f) {
    unsigned u = __float_as_uint(f);
    unsigned r = (u + 0x7FFFu + ((u >> 16) & 1u)) >> 16;
    return (short)r;
}
__device__ inline float bf2f(short s) {
    return __uint_as_float(((unsigned)(unsigned short)s) << 16);
}
__device__ inline float2 bfp2f(int p) {   // packed pair: low short = elem 0
    float2 f;
    f.x = __uint_as_float((unsigned)p << 16);
    f.y = __uint_as_float((unsigned)p & 0xFFFF0000u);
    return f;
}

// ======================= CSR build (by destination) =========================
__global__ __launch_bounds__(256) void count_deg(const int* __restrict__ dst,
                                                 int* __restrict__ cnt, int E) {
    int e = blockIdx.x * 256 + threadIdx.x;
    if (e < E) atomicAdd(&cnt[dst[e]], 1);
}

__global__ __launch_bounds__(256) void scan_block(const int* __restrict__ cnt,
                                                  int* __restrict__ rowptr,
                                                  int* __restrict__ bsum, int N) {
    __shared__ int s[256];
    int tid = threadIdx.x;
    int g = blockIdx.x * 256 + tid;
    int v = (g < N) ? cnt[g] : 0;
    s[tid] = v;
    __syncthreads();
    for (int off = 1; off < 256; off <<= 1) {
        int t = (tid >= off) ? s[tid - off] : 0;
        __syncthreads();
        s[tid] += t;
        __syncthreads();
    }
    if (g < N) rowptr[g] = s[tid] - v;
    if (tid == 255) bsum[blockIdx.x] = s[255];
}

__global__ __launch_bounds__(256) void scan_sums(int* __restrict__ bsum, int nb) {
    __shared__ int s[256];
    int tid = threadIdx.x;
    int v = (tid < nb) ? bsum[tid] : 0;
    s[tid] = v;
    __syncthreads();
    for (int off = 1; off < 256; off <<= 1) {
        int t = (tid >= off) ? s[tid - off] : 0;
        __syncthreads();
        s[tid] += t;
        __syncthreads();
    }
    if (tid < nb) bsum[tid] = s[tid] - v;
}

__global__ __launch_bounds__(256) void scan_add(int* __restrict__ rowptr,
                                                const int* __restrict__ bsum,
                                                int N, int E) {
    int g = blockIdx.x * 256 + threadIdx.x;
    if (g < N) rowptr[g] += bsum[blockIdx.x];
    if (g == 0) rowptr[N] = E;
}

__global__ __launch_bounds__(256) void fill_col(const int* __restrict__ src,
                                                const int* __restrict__ dst,
                                                const int* __restrict__ rowptr,
                                                int* __restrict__ cnt,
                                                int* __restrict__ col, int E) {
    int e = blockIdx.x * 256 + threadIdx.x;
    if (e < E) {
        int d = dst[e];
        int p = atomicAdd(&cnt[d], 1);
        col[rowptr[d] + p] = src[e];
    }
}

// ======================= converts ===========================================
__global__ __launch_bounds__(256) void cvt_x(const float* __restrict__ in,
                                             short* __restrict__ out, int n4) {
    int i = blockIdx.x * 256 + threadIdx.x;
    if (i < n4) {
        float4 v = ((const float4*)in)[i];
        short4 s;
        s.x = f2bf(v.x); s.y = f2bf(v.y); s.z = f2bf(v.z); s.w = f2bf(v.w);
        *(short4*)(out + (size_t)i * 4) = s;
    }
}

__global__ __launch_bounds__(256) void cvt_weights(
    const float* __restrict__ p0, const float* __restrict__ p1,
    const float* __restrict__ p2, const float* __restrict__ p3,
    const float* __restrict__ p4, const float* __restrict__ p5,
    const float* __restrict__ p6, const float* __restrict__ p7,
    short* __restrict__ out) {
    int g = blockIdx.x * 256 + threadIdx.x;
    if (g >= 196608) return;
    const float* src; int off;
    if      (g <  32768) { src = p0; off = g; }
    else if (g <  65536) { src = p1; off = g -  32768; }
    else if (g <  81920) { src = p2; off = g -  65536; }
    else if (g <  98304) { src = p3; off = g -  81920; }
    else if (g < 114688) { src = p4; off = g -  98304; }
    else if (g < 131072) { src = p5; off = g - 114688; }
    else if (g < 163840) { src = p6; off = g - 131072; }
    else                 { src = p7; off = g - 163840; }
    out[g] = f2bf(src[off]);
}

// ============ gather-sum over bf16 rows -> bf16 agg (fp32 accumulate) =======
template<int D>
__global__ __launch_bounds__(256) void gather_sum_bf(
    const short* __restrict__ xbf, const int* __restrict__ rowptr,
    const int* __restrict__ col, short* __restrict__ aggbf, int N)
{
    const int wave = threadIdx.x >> 6;
    const int lane = threadIdx.x & 63;
    const int node = blockIdx.x * 4 + wave;
    if (node >= N) return;
    const int beg = rowptr[node], end = rowptr[node + 1];
    int e = beg;
    if (D == 128) {
        float2 acc = make_float2(0.f, 0.f);
        for (; e + 4 <= end; e += 4) {
            int s0 = col[e], s1 = col[e+1], s2 = col[e+2], s3 = col[e+3];
            int p0 = ((const int*)(xbf + (size_t)s0 * D))[lane];
            int p1 = ((const int*)(xbf + (size_t)s1 * D))[lane];
            int p2 = ((const int*)(xbf + (size_t)s2 * D))[lane];
            int p3 = ((const int*)(xbf + (size_t)s3 * D))[lane];
            float2 f0 = bfp2f(p0), f1 = bfp2f(p1), f2 = bfp2f(p2), f3 = bfp2f(p3);
            acc.x += f0.x + f1.x + f2.x + f3.x;
            acc.y += f0.y + f1.y + f2.y + f3.y;
        }
        for (; e < end; e++) {
            float2 f = bfp2f(((const int*)(xbf + (size_t)col[e] * D))[lane]);
            acc.x += f.x; acc.y += f.y;
        }
        short2 s; s.x = f2bf(acc.x); s.y = f2bf(acc.y);
        *(short2*)(aggbf + (size_t)node * D + lane * 2) = s;
    } else {
        float acc = 0.f;
        for (; e + 4 <= end; e += 4) {
            int s0 = col[e], s1 = col[e+1], s2 = col[e+2], s3 = col[e+3];
            acc += bf2f(xbf[(size_t)s0 * D + lane]) + bf2f(xbf[(size_t)s1 * D + lane])
                 + bf2f(xbf[(size_t)s2 * D + lane]) + bf2f(xbf[(size_t)s3 * D + lane]);
        }
        for (; e < end; e++) acc += bf2f(xbf[(size_t)col[e] * D + lane]);
        aggbf[(size_t)node * D + lane] = f2bf(acc);
    }
}

// ==== gather + epilogue: out = lrelu(seg_sum(z[src]) + w + b), zw bf16 ======
template<int D>
__global__ __launch_bounds__(256) void gather_fin(
    const short* __restrict__ zw, const int* __restrict__ rowptr,
    const int* __restrict__ col, const float* __restrict__ bias,
    float* __restrict__ out, short* __restrict__ out_bf, int N)
{
    const int wave = threadIdx.x >> 6;
    const int lane = threadIdx.x & 63;
    const int node = blockIdx.x * 4 + wave;
    if (node >= N) return;
    const int beg = rowptr[node], end = rowptr[node + 1];
    int e = beg;
    if (D == 128) {
        float2 acc = bfp2f(((const int*)(zw + (size_t)node * 256 + 128))[lane]);
        float2 bb = *(const float2*)(bias + lane * 2);
        acc.x += bb.x; acc.y += bb.y;
        for (; e + 4 <= end; e += 4) {
            int s0 = col[e], s1 = col[e+1], s2 = col[e+2], s3 = col[e+3];
            float2 f0 = bfp2f(((const int*)(zw + (size_t)s0 * 256))[lane]);
            float2 f1 = bfp2f(((const int*)(zw + (size_t)s1 * 256))[lane]);
            float2 f2 = bfp2f(((const int*)(zw + (size_t)s2 * 256))[lane]);
            float2 f3 = bfp2f(((const int*)(zw + (size_t)s3 * 256))[lane]);
            acc.x += f0.x + f1.x + f2.x + f3.x;
            acc.y += f0.y + f1.y + f2.y + f3.y;
        }
        for (; e < end; e++) {
            float2 f = bfp2f(((const int*)(zw + (size_t)col[e] * 256))[lane]);
            acc.x += f.x; acc.y += f.y;
        }
        acc.x = acc.x > 0.f ? acc.x : 0.01f * acc.x;
        acc.y = acc.y > 0.f ? acc.y : 0.01f * acc.y;
        *(float2*)(out + (size_t)node * D + lane * 2) = acc;
        if (out_bf) {
            short2 s; s.x = f2bf(acc.x); s.y = f2bf(acc.y);
            *(short2*)(out_bf + (size_t)node * D + lane * 2) = s;
        }
    } else {
        float acc = bf2f(zw[(size_t)node * 128 + 64 + lane]) + bias[lane];
        for (; e + 4 <= end; e += 4) {
            int s0 = col[e], s1 = col[e+1], s2 = col[e+2], s3 = col[e+3];
            acc += bf2f(zw[(size_t)s0 * 128 + lane]) + bf2f(zw[(size_t)s1 * 128 + lane])
                 + bf2f(zw[(size_t)s2 * 128 + lane]) + bf2f(zw[(size_t)s3 * 128 + lane]);
        }
        for (; e < end; e++) acc += bf2f(zw[(size_t)col[e] * 128 + lane]);
        acc = acc > 0.f ? acc : 0.01f * acc;
        out[(size_t)node * D + lane] = acc;
        if (out_bf) out_bf[(size_t)node * D + lane] = f2bf(acc);
    }
}

// ======================= MFMA GEMM (barrier-free K-loop) ====================
// FUSED: outH = bf16(lrelu([A0|A1] @ [B0|B1]^T + bias)), Ktot=2*DK, Ncols=DOUT
// PRE:   outH = bf16(A0 @ [B0;B1]^T),                    Ktot=DK,  Ncols=2*DOUT
// Tile 128x128, 4 waves 2x2 (each 64x64 via 4x4 frags of 16x16x32).
// B staged ONCE into LDS in MFMA-fragment order (one barrier); A fragments
// load directly global->register; K-loop fully unrolled, no barriers.
template<int DK, int DOUT, bool FUSED>
__global__ __launch_bounds__(256) void gemm_mfma(
    const short* __restrict__ A0, const short* __restrict__ A1,
    const short* __restrict__ B0, const short* __restrict__ B1,
    const float* __restrict__ bias, short* __restrict__ outH, int N)
{
    constexpr int KTOT  = FUSED ? 2 * DK : DK;
    constexpr int NCOLS = FUSED ? DOUT : 2 * DOUT;
    constexpr int K32   = KTOT / 32;          // k-iterations
    constexpr int KSEG  = KTOT / 8;           // int4 segments per B' row
    constexpr int BSH   = 128 * KTOT;         // B tile in shorts
    constexpr int SMSH  = (BSH > 18432) ? BSH : 18432;

    __shared__ short smem[SMSH];
    const int tid  = threadIdx.x;
    const int row0 = blockIdx.x * 128;
    const int col0 = blockIdx.y * 128;
    const int w    = tid >> 6;
    const int lane = tid & 63;
    const int wr   = (w & 1) << 6;
    const int wc   = (w >> 1) << 6;
    const int m16  = lane & 15;
    const int quad = lane >> 4;

    // ---- stage B' tile into LDS, pre-swizzled to fragment order ----
    // frag addr (shorts): (((jj*K32 + kk)*4 + quad)*16 + m16) * 8
    #pragma unroll
    for (int it = 0; it < BSH / 8 / 256; it++) {
        int idx = tid + it * 256;             // one int4 each
        int j = idx / KSEG;                   // col within block (0..127)
        int t = idx % KSEG;                   // 8-short k-segment
        int gj = col0 + j;
        const short* bp;
        int ko = t * 8;
        if (FUSED) {
            if (ko < DK) bp = B0 + (size_t)gj * DK + ko;
            else         bp = B1 + (size_t)gj * DK + (ko - DK);
        } else {
            bp = (gj < DOUT) ? (B0 + (size_t)gj * DK + ko)
                             : (B1 + (size_t)(gj - DOUT) * DK + ko);
        }
        int4 v = *(const int4*)bp;
        int kk = t >> 2, qd = t & 3, jj = j >> 4, mm = j & 15;
        *(int4*)(smem + ((((jj * K32 + kk) * 4 + qd) * 16 + mm) << 3)) = v;
    }
    __syncthreads();

    // ---- A fragment row pointers (clamped) ----
    const short* arow[4];
    #pragma unroll
    for (int i = 0; i < 4; i++) {
        int r = row0 + wr + i * 16 + m16;
        r = r < N ? r : N - 1;
        arow[i] = A0 + (size_t)r * DK;        // A1 offset handled per-kk
    }
    const size_t a1delta = (size_t)(A1 - A0); // valid only if FUSED

    f32x4 acc[4][4] = {};
    const int jw = wc >> 4;

    #pragma unroll
    for (int kk = 0; kk < K32; kk++) {
        const int ko = kk * 32;
        bf16x8 af[4];
        #pragma unroll
        for (int i = 0; i < 4; i++) {
            const short* ap = arow[i] + (quad << 3);
            if (FUSED && ko >= DK) ap += a1delta + (ko - DK);
            else                   ap += ko;
            af[i] = *(const bf16x8*)ap;
        }
        #pragma unroll
        for (int j = 0; j < 4; j++) {
            bf16x8 bfr = *(const bf16x8*)(smem +
                (((((jw + j) * K32 + kk) * 4 + quad) * 16 + m16) << 3));
            #pragma unroll
            for (int i = 0; i < 4; i++)
                acc[i][j] = __builtin_amdgcn_mfma_f32_16x16x32_bf16(
                    af[i], bfr, acc[i][j], 0, 0, 0);
        }
    }

    // ---- epilogue: per-wave LDS transpose -> full-line bf16 stores ----
    __syncthreads();                          // done reading B
    short* ep = smem + w * 4608;              // 64 rows x 72 shorts
    #pragma unroll
    for (int j = 0; j < 4; j++) {
        const int colg = col0 + wc + j * 16 + m16;
        const float bv = FUSED ? bias[colg] : 0.f;
        #pragma unroll
        for (int i = 0; i < 4; i++) {
            #pragma unroll
            for (int r = 0; r < 4; r++) {
                float v = acc[i][j][r];
                if (FUSED) { v += bv; v = v > 0.f ? v : 0.01f * v; }
                ep[(i * 16 + quad * 4 + r) * 72 + j * 16 + m16] = f2bf(v);
            }
        }
    }
    const int r8  = lane >> 3;
    const int seg = lane & 7;
    #pragma unroll
    for (int rb = 0; rb < 8; rb++) {
        const int lrow = rb * 8 + r8;
        int4 vv = *(const int4*)(ep + lrow * 72 + seg * 8);
        const int grow = row0 + wr + lrow;
        if (grow < N)
            *(int4*)(outH + (size_t)grow * NCOLS + col0 + wc + seg * 8) = vv;
    }
}

extern "C" void kernel_launch(void* const* d_in, const int* in_sizes, int n_in,
                              void* d_out, int out_size, void* d_ws, size_t ws_size,
                              hipStream_t stream) {
    const int N = NNODES;
    const float* x  = (const float*)d_in[0];
    const int*   ei = (const int*)d_in[1];
    const int    E  = in_sizes[1] / 2;
    const int* src = ei;
    const int* dst = ei + E;

    const float* Wr[4] = { (const float*)d_in[2], (const float*)d_in[5],
                           (const float*)d_in[8], (const float*)d_in[11] };
    const float* Ws[4] = { (const float*)d_in[3], (const float*)d_in[6],
                           (const float*)d_in[9], (const float*)d_in[12] };
    const float* bb[4] = { (const float*)d_in[4], (const float*)d_in[7],
                           (const float*)d_in[10], (const float*)d_in[13] };

    float* out  = (float*)d_out;                     // h_final: N x 128 fp32
    float* emb  = out + (size_t)N * 128;             // emb:     N x 64 fp32

    // workspace layout (all bf16 activations)
    short* zwbf   = (short*)d_ws;                    // N x 256 bf16 (z|w)
    short* aggbf  = zwbf + (size_t)N * 256;          // N x 256 bf16
    short* xbf    = aggbf + (size_t)N * 256;         // N x 128 bf16
    short* h1bf   = xbf + (size_t)N * 128;           // N x 256 bf16 (also h3)
    short* embbf  = h1bf + (size_t)N * 256;          // N x 64 bf16
    short* wbf    = embbf + (size_t)N * 64;          // 196608 bf16 weights
    int*   rowptr = (int*)(wbf + 196608);            // N+1
    int*   cnt    = rowptr + (N + 1);                // N
    int*   col    = cnt + N;                         // E
    int*   bsum   = col + E;                         // ceil(N/256)

    const short* wr0 = wbf;           const short* ws0 = wbf + 32768;
    const short* wr1 = wbf + 65536;   const short* ws1 = wbf + 81920;
    const short* wr2 = wbf + 98304;   const short* ws2 = wbf + 114688;
    const short* wr3 = wbf + 131072;  const short* ws3 = wbf + 163840;

    const int nb = (N + 255) / 256;
    const int eb = (E + 255) / 256;
    const int gemmRB = (N + 127) / 128;              // 391
    const int nodeBlocks = (N + 3) / 4;

    // ---- CSR build + converts ----
    hipMemsetAsync(cnt, 0, (size_t)N * sizeof(int), stream);
    count_deg<<<eb, 256, 0, stream>>>(dst, cnt, E);
    scan_block<<<nb, 256, 0, stream>>>(cnt, rowptr, bsum, N);
    scan_sums<<<1, 256, 0, stream>>>(bsum, nb);
    scan_add<<<nb, 256, 0, stream>>>(rowptr, bsum, N, E);
    hipMemsetAsync(cnt, 0, (size_t)N * sizeof(int), stream);
    fill_col<<<eb, 256, 0, stream>>>(src, dst, rowptr, cnt, col, E);
    cvt_x<<<(N * 128 / 4 + 255) / 256, 256, 0, stream>>>(x, xbf, N * 128 / 4);
    cvt_weights<<<(196608 + 255) / 256, 256, 0, stream>>>(
        Wr[0], Ws[0], Wr[1], Ws[1], Wr[2], Ws[2], Wr[3], Ws[3], wbf);

    // ---- Layer 0 (gather-first): 128 -> 256 ----
    gather_sum_bf<128><<<nodeBlocks, 256, 0, stream>>>(xbf, rowptr, col, aggbf, N);
    gemm_mfma<128, 256, true><<<dim3(gemmRB, 2), 256, 0, stream>>>(
        aggbf, xbf, wr0, ws0, bb[0], h1bf, N);

    // ---- Layer 1 (GEMM-first): 256 -> 64 ----
    gemm_mfma<256, 64, false><<<dim3(gemmRB, 1), 256, 0, stream>>>(
        h1bf, nullptr, wr1, ws1, nullptr, zwbf, N);            // zw1: N x 128
    gather_fin<64><<<nodeBlocks, 256, 0, stream>>>(
        zwbf, rowptr, col, bb[1], emb, embbf, N);

    // ---- Layer 2 (gather-first): 64 -> 256 ----
    gather_sum_bf<64><<<nodeBlocks, 256, 0, stream>>>(embbf, rowptr, col, aggbf, N);
    gemm_mfma<64, 256, true><<<dim3(gemmRB, 2), 256, 0, stream>>>(
        aggbf, embbf, wr2, ws2, bb[2], h1bf /*h3bf*/, N);

    // ---- Layer 3 (GEMM-first): 256 -> 128 ----
    gemm_mfma<256, 128, false><<<dim3(gemmRB, 2), 256, 0, stream>>>(
        h1bf /*h3bf*/, nullptr, wr3, ws3, nullptr, zwbf, N);   // zw3: N x 256
    gather_fin<128><<<nodeBlocks, 256, 0, stream>>>(
        zwbf, rowptr, col, bb[3], out, nullptr, N);
}